// Round 4
// baseline (445.788 us; speedup 1.0000x reference)
//
#include <hip/hip_runtime.h>
#include <hip/hip_bf16.h>

// GCN: 2x GCNConv(+self-loops, sym-norm) + ReLU, then Linear(64->1).
// N=100000 nodes, E=1600000 edges, IN=128, HID=64, OUT=1.
//
//  - R3 fix: scatter_edges wrote 155MB HBM (12.8MB logical) -> write-line
//    amplification. norm is now factored: out[d] = dq_d*(Ts[d]+sum Ts[s]),
//    Ts = dq-scaled GEMM output (scaled in epilogue). Scatter writes ONLY
//    col (4B/edge); no nrm array, cursor pre-set to row_off.
//  - 64x64 tiled GEMM, 4x4 register blocking, LDS-staged transposed X.
//  - agg: one wave per node, edge loop unrolled x8, scalarized gather base.

#define IN_DIM 128
#define HID 64

// ---------------- degree count ----------------
__global__ void count_deg(const int* __restrict__ dst, int* __restrict__ deg, int E) {
    int i = blockIdx.x * blockDim.x + threadIdx.x;
    if (i < E) atomicAdd(&deg[dst[i]], 1);
}

// ---------------- multi-block exclusive scan over deg -> row_off ----------------
__global__ __launch_bounds__(256) void scan_pass1(const int* __restrict__ deg,
                                                  int* __restrict__ bsum, int n) {
    int i = blockIdx.x * 256 + threadIdx.x;
    int v = (i < n) ? deg[i] : 0;
#pragma unroll
    for (int o = 32; o; o >>= 1) v += __shfl_down(v, o, 64);
    __shared__ int ws[4];
    int lane = threadIdx.x & 63, wid = threadIdx.x >> 6;
    if (lane == 0) ws[wid] = v;
    __syncthreads();
    if (threadIdx.x == 0) bsum[blockIdx.x] = ws[0] + ws[1] + ws[2] + ws[3];
}

__global__ __launch_bounds__(512) void scan_pass2(const int* __restrict__ bsum,
                                                  int* __restrict__ boff,
                                                  int* __restrict__ row_off,
                                                  int nb, int n) {
    __shared__ int s[512];
    int t = threadIdx.x;
    int v = (t < nb) ? bsum[t] : 0;
    s[t] = v;
    __syncthreads();
#pragma unroll
    for (int o = 1; o < 512; o <<= 1) {
        int add = (t >= o) ? s[t - o] : 0;
        __syncthreads();
        s[t] += add;
        __syncthreads();
    }
    if (t < nb) boff[t] = s[t] - v;  // exclusive
    if (t == nb - 1) row_off[n] = s[t];
}

// pass3: row_off + disqrt + cursor(=row_off, absolute alloc cursor)
__global__ __launch_bounds__(256) void scan_pass3(const int* __restrict__ deg,
                                                  const int* __restrict__ boff,
                                                  int* __restrict__ row_off,
                                                  float* __restrict__ disqrt,
                                                  int* __restrict__ cursor, int n) {
    __shared__ int s[256];
    int i = blockIdx.x * 256 + threadIdx.x;
    int t = threadIdx.x;
    int d = (i < n) ? deg[i] : 0;
    s[t] = d;
    __syncthreads();
#pragma unroll
    for (int o = 1; o < 256; o <<= 1) {
        int add = (t >= o) ? s[t - o] : 0;
        __syncthreads();
        s[t] += add;
        __syncthreads();
    }
    if (i < n) {
        int ro = s[t] - d + boff[blockIdx.x];
        row_off[i] = ro;
        cursor[i] = ro;
        disqrt[i] = rsqrtf((float)(d + 1));  // +1 self-loop
    }
}

// ---------------- scatter: col only (4B/edge) ----------------
__global__ void scatter_edges(const int* __restrict__ src, const int* __restrict__ dst,
                              int* __restrict__ cursor, int* __restrict__ col, int E) {
    int e = blockIdx.x * blockDim.x + threadIdx.x;
    if (e < E) {
        int p = atomicAdd(&cursor[dst[e]], 1);
        col[p] = src[e];
    }
}

// ---------------- tiled GEMM: Ts[n,64] = (X[n,K] @ W[K,64]) * disqrt[n] ----------------
template <int K>
__global__ __launch_bounds__(256) void gemm_tile(const float* __restrict__ X,
                                                 const float* __restrict__ W,
                                                 const float* __restrict__ disqrt,
                                                 float* __restrict__ Ts, int n) {
    __shared__ float xs[32][68];   // [k][m]; stride 68 floats keeps rows 16B-aligned
    __shared__ float ws[32][64];   // [k][c]
    const int tid  = threadIdx.x;
    const int nIdx = tid & 15;     // cols 4*nIdx..+3
    const int mIdx = tid >> 4;     // nodes 4*mIdx..+3
    const int m0   = blockIdx.x * 64;
    float acc[4][4] = {};
    for (int kc = 0; kc < K; kc += 32) {
        int f = tid;
#pragma unroll
        for (int i = 0; i < 2; ++i, f += 256) {
            int r  = f >> 3;           // 0..63
            int kq = f & 7;            // float4 within chunk
            int row = m0 + r;
            float4 g = make_float4(0.f, 0.f, 0.f, 0.f);
            if (row < n) g = *(const float4*)(X + (size_t)row * K + kc + 4 * kq);
            xs[4 * kq + 0][r] = g.x;
            xs[4 * kq + 1][r] = g.y;
            xs[4 * kq + 2][r] = g.z;
            xs[4 * kq + 3][r] = g.w;
        }
        f = tid;
#pragma unroll
        for (int i = 0; i < 2; ++i, f += 256) {
            int kk = f >> 4;           // 0..31
            int cq = f & 15;           // 0..15
            *(float4*)&ws[kk][4 * cq] =
                *(const float4*)(W + (size_t)(kc + kk) * 64 + 4 * cq);
        }
        __syncthreads();
#pragma unroll 4
        for (int k = 0; k < 32; ++k) {
            float4 a = *(const float4*)&xs[k][4 * mIdx];
            float4 b = *(const float4*)&ws[k][4 * nIdx];
            const float* ap = (const float*)&a;
            const float* bp = (const float*)&b;
#pragma unroll
            for (int mi = 0; mi < 4; ++mi)
#pragma unroll
                for (int ni = 0; ni < 4; ++ni)
                    acc[mi][ni] += ap[mi] * bp[ni];
        }
        __syncthreads();
    }
#pragma unroll
    for (int mi = 0; mi < 4; ++mi) {
        int row = m0 + 4 * mIdx + mi;
        if (row < n) {
            float s = disqrt[row];
            *(float4*)(Ts + (size_t)row * 64 + 4 * nIdx) =
                make_float4(acc[mi][0] * s, acc[mi][1] * s,
                            acc[mi][2] * s, acc[mi][3] * s);
        }
    }
}

// ---------------- aggregation: one wave per node, 8 gathers in flight ----------------
// out[d] = relu(disqrt[d] * (Ts[d] + sum_e Ts[col[e]]) + bias)
template <bool FUSE_FC>
__global__ __launch_bounds__(256) void agg_kernel(const float* __restrict__ Ts,
                                                  const int* __restrict__ row_off,
                                                  const int* __restrict__ col,
                                                  const float* __restrict__ disqrt,
                                                  const float* __restrict__ bias,
                                                  const float* __restrict__ wfc,
                                                  const float* __restrict__ bfc,
                                                  float* __restrict__ out, int n) {
    int node = blockIdx.x * 4 + (threadIdx.x >> 6);
    if (node >= n) return;
    int lane = threadIdx.x & 63;
    float acc = Ts[(size_t)node * HID + lane];  // self-loop (pre-scaled)
    int beg = __builtin_amdgcn_readfirstlane(row_off[node]);
    int end = __builtin_amdgcn_readfirstlane(row_off[node + 1]);
    int i = beg;
    for (; i + 8 <= end; i += 8) {
        int s0 = __builtin_amdgcn_readfirstlane(col[i + 0]);
        int s1 = __builtin_amdgcn_readfirstlane(col[i + 1]);
        int s2 = __builtin_amdgcn_readfirstlane(col[i + 2]);
        int s3 = __builtin_amdgcn_readfirstlane(col[i + 3]);
        int s4 = __builtin_amdgcn_readfirstlane(col[i + 4]);
        int s5 = __builtin_amdgcn_readfirstlane(col[i + 5]);
        int s6 = __builtin_amdgcn_readfirstlane(col[i + 6]);
        int s7 = __builtin_amdgcn_readfirstlane(col[i + 7]);
        float g0 = Ts[(size_t)s0 * HID + lane];
        float g1 = Ts[(size_t)s1 * HID + lane];
        float g2 = Ts[(size_t)s2 * HID + lane];
        float g3 = Ts[(size_t)s3 * HID + lane];
        float g4 = Ts[(size_t)s4 * HID + lane];
        float g5 = Ts[(size_t)s5 * HID + lane];
        float g6 = Ts[(size_t)s6 * HID + lane];
        float g7 = Ts[(size_t)s7 * HID + lane];
        acc += g0; acc += g1; acc += g2; acc += g3;
        acc += g4; acc += g5; acc += g6; acc += g7;
    }
    for (; i < end; ++i) {
        int s = __builtin_amdgcn_readfirstlane(col[i]);
        acc += Ts[(size_t)s * HID + lane];
    }
    float r = fmaxf(acc * disqrt[node] + bias[lane], 0.f);
    if (!FUSE_FC) {
        out[(size_t)node * HID + lane] = r;
    } else {
        float v = r * wfc[lane];
        v += __shfl_down(v, 32, 64);
        v += __shfl_down(v, 16, 64);
        v += __shfl_down(v, 8, 64);
        v += __shfl_down(v, 4, 64);
        v += __shfl_down(v, 2, 64);
        v += __shfl_down(v, 1, 64);
        if (lane == 0) out[node] = v + bfc[0];
    }
}

extern "C" void kernel_launch(void* const* d_in, const int* in_sizes, int n_in,
                              void* d_out, int out_size, void* d_ws, size_t ws_size,
                              hipStream_t stream) {
    const float* x   = (const float*)d_in[0];
    const int*   ei  = (const int*)d_in[1];
    const float* W1  = (const float*)d_in[2];
    const float* b1  = (const float*)d_in[3];
    const float* W2  = (const float*)d_in[4];
    const float* b2  = (const float*)d_in[5];
    const float* Wfc = (const float*)d_in[6];
    const float* bfc = (const float*)d_in[7];
    float* out = (float*)d_out;

    const int N = in_sizes[0] / IN_DIM;
    const int E = in_sizes[1] / 2;
    const int* src = ei;
    const int* dst = ei + E;
    const int NB = (N + 255) / 256;  // scan blocks (must be <= 512)

    // ---- workspace carve-up (256B aligned) ----
    char* w = (char*)d_ws;
    auto alloc = [&](size_t bytes) {
        void* p = (void*)w;
        w += (bytes + 255) & ~(size_t)255;
        return p;
    };
    int*   deg     = (int*)alloc((size_t)N * 4);
    int*   row_off = (int*)alloc((size_t)(N + 1) * 4);
    int*   cursor  = (int*)alloc((size_t)N * 4);
    float* disqrt  = (float*)alloc((size_t)N * 4);
    int*   bsum    = (int*)alloc(512 * 4);
    int*   boff    = (int*)alloc(512 * 4);
    int*   col     = (int*)alloc((size_t)E * 4);
    float* t1      = (float*)alloc((size_t)N * HID * 4);  // also reused as t2
    float* h1      = (float*)alloc((size_t)N * HID * 4);

    // ---- build CSR ----
    hipMemsetAsync(deg, 0, (size_t)N * 4, stream);
    count_deg<<<(E + 255) / 256, 256, 0, stream>>>(dst, deg, E);
    scan_pass1<<<NB, 256, 0, stream>>>(deg, bsum, N);
    scan_pass2<<<1, 512, 0, stream>>>(bsum, boff, row_off, NB, N);
    scan_pass3<<<NB, 256, 0, stream>>>(deg, boff, row_off, disqrt, cursor, N);
    scatter_edges<<<(E + 255) / 256, 256, 0, stream>>>(src, dst, cursor, col, E);

    // ---- layer 1 ----
    gemm_tile<IN_DIM><<<(N + 63) / 64, 256, 0, stream>>>(x, W1, disqrt, t1, N);
    agg_kernel<false><<<(N + 3) / 4, 256, 0, stream>>>(t1, row_off, col, disqrt,
                                                       b1, nullptr, nullptr, h1, N);

    // ---- layer 2 + fused fc ----
    gemm_tile<HID><<<(N + 63) / 64, 256, 0, stream>>>(h1, W2, disqrt, t1, N);
    agg_kernel<true><<<(N + 3) / 4, 256, 0, stream>>>(t1, row_off, col, disqrt,
                                                      b2, Wfc, bfc, out, N);
}